// Round 3
// baseline (146.716 us; speedup 1.0000x reference)
//
#include <hip/hip_runtime.h>
#include <hip/hip_bf16.h>

// GraphAttentionLayer: B=2, N=512, D=256, H=4, HD=64, slope=0.2
// Inputs: float32. Outputs: float32 = concat(h_prime [B,N,256], e [B,N,N,4]).
// d_ws: hq, hk, hv as f32, each B*N*256 floats (3 MB total).

#define NB 2
#define NN 512
#define DD 256
#define NH 4
#define HDIM 64
#define SLOPE 0.2f

// ---------------- Projections: hq = q@wq+bq, hk = k@wq+bq, hv = v@wv+bv ----
__global__ __launch_bounds__(256) void proj_kernel(
    const float* __restrict__ q, const float* __restrict__ kin, const float* __restrict__ vin,
    const float* __restrict__ wq, const float* __restrict__ bq,
    const float* __restrict__ wv, const float* __restrict__ bv,
    float* __restrict__ hq, float* __restrict__ hk, float* __restrict__ hv)
{
    const int m = blockIdx.y;                       // 0:q->hq  1:k->hk  2:v->hv
    const float* x    = (m == 0) ? q  : (m == 1) ? kin : vin;
    const float* w    = (m == 2) ? wv : wq;
    const float* bias = (m == 2) ? bv : bq;
    float* out        = (m == 0) ? hq : (m == 1) ? hk : hv;

    const int r0 = blockIdx.x * 8;                  // 8 rows per block
    const int t  = threadIdx.x;                     // output column 0..255
    __shared__ float xs[8][DD];
    #pragma unroll
    for (int r = 0; r < 8; ++r)
        xs[r][t] = x[(size_t)(r0 + r) * DD + t];
    __syncthreads();

    const float bb = bias[t];
    float acc[8];
    #pragma unroll
    for (int r = 0; r < 8; ++r) acc[r] = bb;

    for (int k = 0; k < DD; ++k) {
        const float wval = w[k * DD + t];           // coalesced across threads
        #pragma unroll
        for (int r = 0; r < 8; ++r) acc[r] = fmaf(xs[r][k], wval, acc[r]);
    }
    #pragma unroll
    for (int r = 0; r < 8; ++r)
        out[(size_t)(r0 + r) * DD + t] = acc[r];
}

// ------- Fused: scores + softmax + e-write + PV + relu, per (b, 4 i-rows) --
__global__ __launch_bounds__(256) void attn_kernel(
    const float* __restrict__ hq, const float* __restrict__ hk, const float* __restrict__ hv,
    const float* __restrict__ a, float* __restrict__ out_hp, float* __restrict__ out_e)
{
    const int t  = threadIdx.x;
    const int b  = blockIdx.x >> 7;                 // 128 blocks per batch
    const int i0 = (blockIdx.x & 127) * 4;          // 4 target rows per block

    __shared__ float sk[4][DD];                     // hk rows for i0..i0+3
    __shared__ float sa[HDIM];
    __shared__ float s[16][NN];                     // [ii*4+h][j] scores -> e   32 KB

    #pragma unroll
    for (int ii = 0; ii < 4; ++ii)
        sk[ii][t] = hk[((size_t)(b * NN) + (i0 + ii)) * DD + t];
    if (t < HDIM) sa[t] = a[t];
    __syncthreads();

    // ---- Phase 1: scores. 2048 (h,j) pairs; each thread does 8; the 64-f
    // hq read is shared across the 4 i's of the tile.
    for (int pp = 0; pp < 8; ++pp) {
        const int p = t + 256 * pp;                 // 0..2047
        const int j = p >> 2;
        const int h = p & 3;
        const float* hqp = &hq[((size_t)(b * NN) + j) * DD + h * HDIM];
        const float4* hq4 = reinterpret_cast<const float4*>(hqp);
        const float* sk0 = &sk[0][h * HDIM];
        const float* sk1 = &sk[1][h * HDIM];
        const float* sk2 = &sk[2][h * HDIM];
        const float* sk3 = &sk[3][h * HDIM];
        float acc0 = 0.f, acc1 = 0.f, acc2 = 0.f, acc3 = 0.f;
        #pragma unroll
        for (int fq = 0; fq < HDIM / 4; ++fq) {
            const float4 qv = hq4[fq];
            const float qc[4] = {qv.x, qv.y, qv.z, qv.w};
            #pragma unroll
            for (int c = 0; c < 4; ++c) {
                const int f = fq * 4 + c;
                const float af = sa[f];
                float x0 = qc[c] + sk0[f]; acc0 = fmaf(x0 > 0.f ? x0 : SLOPE * x0, af, acc0);
                float x1 = qc[c] + sk1[f]; acc1 = fmaf(x1 > 0.f ? x1 : SLOPE * x1, af, acc1);
                float x2 = qc[c] + sk2[f]; acc2 = fmaf(x2 > 0.f ? x2 : SLOPE * x2, af, acc2);
                float x3 = qc[c] + sk3[f]; acc3 = fmaf(x3 > 0.f ? x3 : SLOPE * x3, af, acc3);
            }
        }
        s[0 * 4 + h][j] = acc0;
        s[1 * 4 + h][j] = acc1;
        s[2 * 4 + h][j] = acc2;
        s[3 * 4 + h][j] = acc3;
    }
    __syncthreads();

    // ---- Phase 2: softmax over j. Wave w handles ii=w; 64 lanes over 512 j.
    {
        const int ii   = t >> 6;                    // wave index (wave64)
        const int lane = t & 63;
        for (int h = 0; h < 4; ++h) {
            float* row = &s[ii * 4 + h][0];
            float vals[8];
            float mx = -1e30f;
            #pragma unroll
            for (int k2 = 0; k2 < 8; ++k2) { vals[k2] = row[lane + 64 * k2]; mx = fmaxf(mx, vals[k2]); }
            #pragma unroll
            for (int off = 32; off; off >>= 1) mx = fmaxf(mx, __shfl_xor(mx, off, 64));
            float sum = 0.f;
            #pragma unroll
            for (int k2 = 0; k2 < 8; ++k2) { vals[k2] = __expf(vals[k2] - mx); sum += vals[k2]; }
            #pragma unroll
            for (int off = 32; off; off >>= 1) sum += __shfl_xor(sum, off, 64);
            const float inv = 1.0f / sum;
            #pragma unroll
            for (int k2 = 0; k2 < 8; ++k2) row[lane + 64 * k2] = vals[k2] * inv;
        }
    }
    __syncthreads();

    // ---- e write: block's chunk is contiguous: [(b*N+i0)*N*H, +4*N*H).
    {
        const size_t ebase = ((size_t)(b * NN) + i0) * NN * NH;
        #pragma unroll 4
        for (int k2 = 0; k2 < 32; ++k2) {
            const int idx = t + 256 * k2;           // 0..8191 = ii*2048 + j*4 + h
            const int ii  = idx >> 11;
            const int rem = idx & 2047;
            const int j   = rem >> 2;
            const int h   = rem & 3;
            out_e[ebase + idx] = s[ii * 4 + h][j];
        }
    }

    // ---- Phase 3: out[b,i,h,f] = sum_j e * hv; hv load shared across 4 i's.
    {
        const int h = t >> 6;                       // t == h*64+f == output column
        float acc0 = 0.f, acc1 = 0.f, acc2 = 0.f, acc3 = 0.f;
        const float* hvp = &hv[(size_t)(b * NN) * DD + t];
        for (int j = 0; j < NN; ++j) {
            const float hvv = hvp[(size_t)j * DD];  // coalesced 1KB/iter per block
            acc0 = fmaf(s[0 * 4 + h][j], hvv, acc0);
            acc1 = fmaf(s[1 * 4 + h][j], hvv, acc1);
            acc2 = fmaf(s[2 * 4 + h][j], hvv, acc2);
            acc3 = fmaf(s[3 * 4 + h][j], hvv, acc3);
        }
        acc0 = acc0 > 0.f ? acc0 : 0.f;
        acc1 = acc1 > 0.f ? acc1 : 0.f;
        acc2 = acc2 > 0.f ? acc2 : 0.f;
        acc3 = acc3 > 0.f ? acc3 : 0.f;
        out_hp[((size_t)(b * NN) + (i0 + 0)) * DD + t] = acc0;
        out_hp[((size_t)(b * NN) + (i0 + 1)) * DD + t] = acc1;
        out_hp[((size_t)(b * NN) + (i0 + 2)) * DD + t] = acc2;
        out_hp[((size_t)(b * NN) + (i0 + 3)) * DD + t] = acc3;
    }
}

extern "C" void kernel_launch(void* const* d_in, const int* in_sizes, int n_in,
                              void* d_out, int out_size, void* d_ws, size_t ws_size,
                              hipStream_t stream) {
    const float* q   = (const float*)d_in[0];
    const float* kin = (const float*)d_in[1];
    const float* vin = (const float*)d_in[2];
    const float* wq  = (const float*)d_in[3];
    const float* bq  = (const float*)d_in[4];
    const float* wv  = (const float*)d_in[5];
    const float* bv  = (const float*)d_in[6];
    const float* a   = (const float*)d_in[7];

    float* out_hp = (float*)d_out;                    // [B,N,256] = 262144
    float* out_e  = out_hp + (size_t)NB * NN * DD;    // [B,N,N,4] = 2097152

    float* hq = (float*)d_ws;                         // each B*N*256 f32
    float* hk = hq + (size_t)NB * NN * DD;
    float* hv = hk + (size_t)NB * NN * DD;

    proj_kernel<<<dim3(NB * NN / 8, 3), 256, 0, stream>>>(q, kin, vin, wq, bq, wv, bv, hq, hk, hv);
    attn_kernel<<<dim3(NB * NN / 4), 256, 0, stream>>>(hq, hk, hv, a, out_hp, out_e);
}

// Round 4
// 141.511 us; speedup vs baseline: 1.0368x; 1.0368x over previous
//
#include <hip/hip_runtime.h>

// GraphAttentionLayer: B=2, N=512, D=256, H=4, HD=64, slope=0.2
// Inputs f32, outputs f32 = concat(h_prime [B,N,256], e [B,N,N,4]).
// lrelu(x) = 0.6x + 0.4|x|; the hk-dot term is constant in j and cancels in
// softmax, so score = 0.6*u[j,h] + 0.4*sum_f |hq+hk|*a  (u = sum_f hq*a).

#define NB 2
#define NN 512
#define DD 256
#define NH 4
#define HDIM 64

__device__ __forceinline__ float rl(float v, int u) {
    return __uint_as_float(__builtin_amdgcn_readlane(__float_as_uint(v), u));
}

// ---------------- proj: register-blocked GEMM, 16 rows x 128 cols/block ----
__global__ __launch_bounds__(256, 4) void proj_kernel(
    const float* __restrict__ q, const float* __restrict__ kin, const float* __restrict__ vin,
    const float* __restrict__ wq, const float* __restrict__ bq,
    const float* __restrict__ wv, const float* __restrict__ bv,
    float* __restrict__ hq, float* __restrict__ hk, float* __restrict__ hv)
{
    const int m = blockIdx.z;
    const float* x    = (m == 0) ? q  : (m == 1) ? kin : vin;
    const float* w    = (m == 2) ? wv : wq;
    const float* bias = (m == 2) ? bv : bq;
    float* out        = (m == 0) ? hq : (m == 1) ? hk : hv;

    const int r0 = blockIdx.x * 16;
    const int cb = blockIdx.y * 128;
    const int t  = threadIdx.x;

    __shared__ float xs[16][DD + 4];              // stride 260 f (16B-aligned rows)

    #pragma unroll
    for (int p = 0; p < 4; ++p) {                 // stage 16x256 x-tile
        const int idx = t + 256 * p;
        const int row = idx >> 6;
        const int kc  = idx & 63;
        const float4 v = *reinterpret_cast<const float4*>(&x[(size_t)(r0 + row) * DD + kc * 4]);
        *reinterpret_cast<float4*>(&xs[row][kc * 4]) = v;
    }
    __syncthreads();

    const int row0 = (t >> 5) * 2;                // 2 rows per thread
    const int c0   = (t & 31) * 4;                // 4 cols per thread

    const float4 b4 = *reinterpret_cast<const float4*>(&bias[cb + c0]);
    float acc[2][4];
    #pragma unroll
    for (int r = 0; r < 2; ++r) { acc[r][0]=b4.x; acc[r][1]=b4.y; acc[r][2]=b4.z; acc[r][3]=b4.w; }

    for (int kt = 0; kt < DD; kt += 4) {
        const float4 a0 = *reinterpret_cast<const float4*>(&xs[row0][kt]);
        const float4 a1 = *reinterpret_cast<const float4*>(&xs[row0 + 1][kt]);
        const float xa0[4] = {a0.x, a0.y, a0.z, a0.w};
        const float xa1[4] = {a1.x, a1.y, a1.z, a1.w};
        #pragma unroll
        for (int kk = 0; kk < 4; ++kk) {
            const float4 w4 = *reinterpret_cast<const float4*>(&w[(size_t)(kt + kk) * DD + cb + c0]);
            const float wv4[4] = {w4.x, w4.y, w4.z, w4.w};
            #pragma unroll
            for (int c = 0; c < 4; ++c) {
                acc[0][c] = fmaf(xa0[kk], wv4[c], acc[0][c]);
                acc[1][c] = fmaf(xa1[kk], wv4[c], acc[1][c]);
            }
        }
    }
    #pragma unroll
    for (int r = 0; r < 2; ++r) {
        float4 o; o.x = acc[r][0]; o.y = acc[r][1]; o.z = acc[r][2]; o.w = acc[r][3];
        *reinterpret_cast<float4*>(&out[(size_t)(r0 + row0 + r) * DD + cb + c0]) = o;
    }
}

// ------- Fused attention: one block per (b, 4 i-rows), 512 threads ---------
__global__ __launch_bounds__(512, 4) void attn_kernel(
    const float* __restrict__ hq, const float* __restrict__ hk, const float* __restrict__ hv,
    const float* __restrict__ a, float* __restrict__ out_hp, float* __restrict__ out_e)
{
    const int t  = threadIdx.x;
    const int b  = blockIdx.x >> 7;
    const int i0 = (blockIdx.x & 127) * 4;

    __shared__ float skp[4][4][HDIM + 4];         // [ii][h][f], pad kills h-slice conflicts
    __shared__ float sa[HDIM];
    __shared__ float s[16][NN + 8];               // stride 520 (16B-aligned, odd/32 banks)
    __shared__ float part[2][4][DD];              // phase-3 j-half partials

    #pragma unroll
    for (int p = 0; p < 2; ++p) {
        const int idx = t + 512 * p;              // 0..1023
        const int ii = idx >> 8, c = idx & 255;
        skp[ii][c >> 6][c & 63] = hk[((size_t)(b * NN) + i0 + ii) * DD + c];
    }
    if (t < HDIM) sa[t] = a[t];
    __syncthreads();

    // ---- Phase 1: thread = (h, 4 j's); u-dot + 4 abs-sums per j.
    {
        const int h  = t & 3;
        const int jb = (t >> 2) * 4;
        const float* qbase = hq + ((size_t)(b * NN) + jb) * DD + h * HDIM;
        float accu[4] = {0.f, 0.f, 0.f, 0.f};
        float acc[4][4] = {};
        #pragma unroll
        for (int fc = 0; fc < HDIM / 4; ++fc) {
            const float4 a4 = *reinterpret_cast<const float4*>(&sa[fc * 4]);
            const float av[4] = {a4.x, a4.y, a4.z, a4.w};
            float kk[4][4];
            #pragma unroll
            for (int ii = 0; ii < 4; ++ii) {
                const float4 kv = *reinterpret_cast<const float4*>(&skp[ii][h][fc * 4]);
                kk[ii][0]=kv.x; kk[ii][1]=kv.y; kk[ii][2]=kv.z; kk[ii][3]=kv.w;
            }
            #pragma unroll
            for (int jj = 0; jj < 4; ++jj) {
                const float4 q4 = *reinterpret_cast<const float4*>(qbase + jj * DD + fc * 4);
                const float qv[4] = {q4.x, q4.y, q4.z, q4.w};
                #pragma unroll
                for (int c = 0; c < 4; ++c) {
                    accu[jj] = fmaf(qv[c], av[c], accu[jj]);
                    #pragma unroll
                    for (int ii = 0; ii < 4; ++ii)
                        acc[jj][ii] = fmaf(__builtin_fabsf(qv[c] + kk[ii][c]), av[c], acc[jj][ii]);
                }
            }
        }
        #pragma unroll
        for (int jj = 0; jj < 4; ++jj) {
            const float su = 0.6f * accu[jj];
            #pragma unroll
            for (int ii = 0; ii < 4; ++ii)
                s[ii * 4 + h][jb + jj] = fmaf(0.4f, acc[jj][ii], su);
        }
    }
    __syncthreads();

    // ---- Phase 2: softmax over j; 8 waves x 2 rows.
    {
        const int wv = t >> 6, lane = t & 63;
        #pragma unroll
        for (int rr = 0; rr < 2; ++rr) {
            float* row = &s[wv * 2 + rr][0];
            float vals[8]; float mx = -1e30f;
            #pragma unroll
            for (int k2 = 0; k2 < 8; ++k2) { vals[k2] = row[lane + 64 * k2]; mx = fmaxf(mx, vals[k2]); }
            #pragma unroll
            for (int off = 32; off; off >>= 1) mx = fmaxf(mx, __shfl_xor(mx, off, 64));
            float sum = 0.f;
            #pragma unroll
            for (int k2 = 0; k2 < 8; ++k2) { vals[k2] = __expf(vals[k2] - mx); sum += vals[k2]; }
            #pragma unroll
            for (int off = 32; off; off >>= 1) sum += __shfl_xor(sum, off, 64);
            const float inv = 1.0f / sum;
            #pragma unroll
            for (int k2 = 0; k2 < 8; ++k2) row[lane + 64 * k2] = vals[k2] * inv;
        }
    }
    __syncthreads();

    // ---- e-write: one float4 (= one (ii,j), h=0..3) per thread x 4.
    {
        float4* oe4 = reinterpret_cast<float4*>(out_e + ((size_t)(b * NN) + i0) * NN * NH);
        #pragma unroll
        for (int k2 = 0; k2 < 4; ++k2) {
            const int fi = t + 512 * k2;          // 0..2047
            const int ii = fi >> 9;
            const int j  = fi & 511;
            float4 o;
            o.x = s[ii * 4 + 0][j]; o.y = s[ii * 4 + 1][j];
            o.z = s[ii * 4 + 2][j]; o.w = s[ii * 4 + 3][j];
            oe4[fi] = o;
        }
    }

    // ---- Phase 3: thread = (col, j-half); e broadcast via readlane (VALU,
    // not LDS pipe); hv read once per block, coalesced.
    {
        const int col  = t & 255;
        const int jh   = t >> 8;                  // wave-uniform
        const int h    = col >> 6;                // wave-uniform
        const int lane = t & 63;
        float acc[4] = {0.f, 0.f, 0.f, 0.f};
        const float* hvb = hv + (size_t)(b * NN) * DD + col;
        #pragma unroll
        for (int ch = 0; ch < 4; ++ch) {
            const int jbase = jh * 256 + ch * 64;
            const float e0 = s[0 * 4 + h][jbase + lane];   // coalesced chunk loads
            const float e1 = s[1 * 4 + h][jbase + lane];
            const float e2 = s[2 * 4 + h][jbase + lane];
            const float e3 = s[3 * 4 + h][jbase + lane];
            #pragma unroll
            for (int u = 0; u < 64; ++u) {
                const float hvv = hvb[(size_t)(jbase + u) * DD];
                acc[0] = fmaf(rl(e0, u), hvv, acc[0]);
                acc[1] = fmaf(rl(e1, u), hvv, acc[1]);
                acc[2] = fmaf(rl(e2, u), hvv, acc[2]);
                acc[3] = fmaf(rl(e3, u), hvv, acc[3]);
            }
        }
        #pragma unroll
        for (int ii = 0; ii < 4; ++ii) part[jh][ii][col] = acc[ii];
    }
    __syncthreads();
    {
        #pragma unroll
        for (int r = 0; r < 2; ++r) {
            const int idx = t + 512 * r;          // 0..1023
            const int ii = idx >> 8, col = idx & 255;
            const float v = part[0][ii][col] + part[1][ii][col];
            out_hp[((size_t)(b * NN) + i0 + ii) * DD + col] = v > 0.f ? v : 0.f;
        }
    }
}

extern "C" void kernel_launch(void* const* d_in, const int* in_sizes, int n_in,
                              void* d_out, int out_size, void* d_ws, size_t ws_size,
                              hipStream_t stream) {
    const float* q   = (const float*)d_in[0];
    const float* kin = (const float*)d_in[1];
    const float* vin = (const float*)d_in[2];
    const float* wq  = (const float*)d_in[3];
    const float* bq  = (const float*)d_in[4];
    const float* wv  = (const float*)d_in[5];
    const float* bv  = (const float*)d_in[6];
    const float* a   = (const float*)d_in[7];

    float* out_hp = (float*)d_out;                    // [B,N,256]
    float* out_e  = out_hp + (size_t)NB * NN * DD;    // [B,N,N,4]

    float* hq = (float*)d_ws;                         // each B*N*256 f32
    float* hk = hq + (size_t)NB * NN * DD;
    float* hv = hk + (size_t)NB * NN * DD;

    proj_kernel<<<dim3(64, 2, 3), 256, 0, stream>>>(q, kin, vin, wq, bq, wv, bv, hq, hk, hv);
    attn_kernel<<<dim3(NB * NN / 4), 512, 0, stream>>>(hq, hk, hv, a, out_hp, out_e);
}

// Round 5
// 134.682 us; speedup vs baseline: 1.0894x; 1.0507x over previous
//
#include <hip/hip_runtime.h>

// GraphAttentionLayer: B=2, N=512, D=256, H=4, HD=64, slope=0.2
// Inputs f32, outputs f32 = concat(h_prime [B,N,256], e [B,N,N,4]).
// lrelu(x) = 0.6x + 0.4|x|; hk-dot term is j-constant -> cancels in softmax:
// score = 0.6*sum_f hq*a + 0.4*sum_f |hq+hk|*a.
// attn grid: (b, i-tile of 4, h-pair) = 512 blocks x 512 thr -> 2 blocks/CU.

#define NB 2
#define NN 512
#define DD 256
#define NH 4
#define HDIM 64

__device__ __forceinline__ float rl(float v, int u) {
    return __uint_as_float(__builtin_amdgcn_readlane(__float_as_uint(v), u));
}

// ---------------- proj: register-blocked GEMM, 16 rows x 128 cols/block ----
__global__ __launch_bounds__(256, 4) void proj_kernel(
    const float* __restrict__ q, const float* __restrict__ kin, const float* __restrict__ vin,
    const float* __restrict__ wq, const float* __restrict__ bq,
    const float* __restrict__ wv, const float* __restrict__ bv,
    float* __restrict__ hq, float* __restrict__ hk, float* __restrict__ hv)
{
    const int m = blockIdx.z;
    const float* x    = (m == 0) ? q  : (m == 1) ? kin : vin;
    const float* w    = (m == 2) ? wv : wq;
    const float* bias = (m == 2) ? bv : bq;
    float* out        = (m == 0) ? hq : (m == 1) ? hk : hv;

    const int r0 = blockIdx.x * 16;
    const int cb = blockIdx.y * 128;
    const int t  = threadIdx.x;

    __shared__ float xs[16][DD + 4];

    #pragma unroll
    for (int p = 0; p < 4; ++p) {
        const int idx = t + 256 * p;
        const int row = idx >> 6;
        const int kc  = idx & 63;
        const float4 v = *reinterpret_cast<const float4*>(&x[(size_t)(r0 + row) * DD + kc * 4]);
        *reinterpret_cast<float4*>(&xs[row][kc * 4]) = v;
    }
    __syncthreads();

    const int row0 = (t >> 5) * 2;
    const int c0   = (t & 31) * 4;

    const float4 b4 = *reinterpret_cast<const float4*>(&bias[cb + c0]);
    float acc[2][4];
    #pragma unroll
    for (int r = 0; r < 2; ++r) { acc[r][0]=b4.x; acc[r][1]=b4.y; acc[r][2]=b4.z; acc[r][3]=b4.w; }

    for (int kt = 0; kt < DD; kt += 4) {
        const float4 a0 = *reinterpret_cast<const float4*>(&xs[row0][kt]);
        const float4 a1 = *reinterpret_cast<const float4*>(&xs[row0 + 1][kt]);
        const float xa0[4] = {a0.x, a0.y, a0.z, a0.w};
        const float xa1[4] = {a1.x, a1.y, a1.z, a1.w};
        #pragma unroll
        for (int kk = 0; kk < 4; ++kk) {
            const float4 w4 = *reinterpret_cast<const float4*>(&w[(size_t)(kt + kk) * DD + cb + c0]);
            const float wv4[4] = {w4.x, w4.y, w4.z, w4.w};
            #pragma unroll
            for (int c = 0; c < 4; ++c) {
                acc[0][c] = fmaf(xa0[kk], wv4[c], acc[0][c]);
                acc[1][c] = fmaf(xa1[kk], wv4[c], acc[1][c]);
            }
        }
    }
    #pragma unroll
    for (int r = 0; r < 2; ++r) {
        float4 o; o.x = acc[r][0]; o.y = acc[r][1]; o.z = acc[r][2]; o.w = acc[r][3];
        *reinterpret_cast<float4*>(&out[(size_t)(r0 + row0 + r) * DD + cb + c0]) = o;
    }
}

// -------- attn: block = (b, 4 i-rows, h-pair), 512 threads, 8 waves --------
__global__ __launch_bounds__(512, 4) void attn_kernel(
    const float* __restrict__ hq, const float* __restrict__ hk, const float* __restrict__ hv,
    const float* __restrict__ a, float* __restrict__ out_hp, float* __restrict__ out_e)
{
    const int t   = threadIdx.x;
    const int b   = blockIdx.x >> 8;
    const int rem = blockIdx.x & 255;
    const int i0  = (rem >> 1) * 4;
    const int hp  = rem & 1;                      // h-pair: heads {2hp, 2hp+1}

    __shared__ float skp[4][2][HDIM + 4];         // [ii][hl][f]
    __shared__ float sa[HDIM];
    __shared__ float s[8][NN + 8];                // [ii*2+hl][j]  16.6 KB
    __shared__ float part[4][4][128];             // [jg][ii][col] 8 KB

    {   // stage hk h-slice: 4 ii x 128 cols
        const int ii = t >> 7, c = t & 127;
        skp[ii][c >> 6][c & 63] = hk[((size_t)(b * NN) + i0 + ii) * DD + hp * 128 + c];
    }
    if (t < HDIM) sa[t] = a[t];
    __syncthreads();

    // ---- Phase 1: thread = (hl, j-duo); 4-ii kk reuse per fc.
    {
        const int hl = t & 1;
        const int j0 = (t >> 1) * 2;
        const float* qbase = hq + ((size_t)(b * NN) + j0) * DD + (hp * 2 + hl) * HDIM;
        float accu[2] = {0.f, 0.f};
        float acc[2][4] = {};
        #pragma unroll
        for (int fc = 0; fc < HDIM / 4; ++fc) {
            const float4 a4 = *reinterpret_cast<const float4*>(&sa[fc * 4]);
            const float av[4] = {a4.x, a4.y, a4.z, a4.w};
            float kk[4][4];
            #pragma unroll
            for (int ii = 0; ii < 4; ++ii) {
                const float4 kv = *reinterpret_cast<const float4*>(&skp[ii][hl][fc * 4]);
                kk[ii][0]=kv.x; kk[ii][1]=kv.y; kk[ii][2]=kv.z; kk[ii][3]=kv.w;
            }
            #pragma unroll
            for (int jj = 0; jj < 2; ++jj) {
                const float4 q4 = *reinterpret_cast<const float4*>(qbase + jj * DD + fc * 4);
                const float qv[4] = {q4.x, q4.y, q4.z, q4.w};
                #pragma unroll
                for (int c = 0; c < 4; ++c) {
                    accu[jj] = fmaf(qv[c], av[c], accu[jj]);
                    #pragma unroll
                    for (int ii = 0; ii < 4; ++ii)
                        acc[jj][ii] = fmaf(__builtin_fabsf(qv[c] + kk[ii][c]), av[c], acc[jj][ii]);
                }
            }
        }
        #pragma unroll
        for (int jj = 0; jj < 2; ++jj) {
            const float su = 0.6f * accu[jj];
            #pragma unroll
            for (int ii = 0; ii < 4; ++ii)
                s[ii * 2 + hl][j0 + jj] = fmaf(0.4f, acc[jj][ii], su);
        }
    }
    __syncthreads();

    // ---- Phase 2: softmax over j; 8 waves x 8 rows -> 1 row/wave.
    {
        const int wv = t >> 6, lane = t & 63;
        float* row = &s[wv][0];
        float vals[8]; float mx = -1e30f;
        #pragma unroll
        for (int k2 = 0; k2 < 8; ++k2) { vals[k2] = row[lane + 64 * k2]; mx = fmaxf(mx, vals[k2]); }
        #pragma unroll
        for (int off = 32; off; off >>= 1) mx = fmaxf(mx, __shfl_xor(mx, off, 64));
        float sum = 0.f;
        #pragma unroll
        for (int k2 = 0; k2 < 8; ++k2) { vals[k2] = __expf(vals[k2] - mx); sum += vals[k2]; }
        #pragma unroll
        for (int off = 32; off; off >>= 1) sum += __shfl_xor(sum, off, 64);
        const float inv = 1.0f / sum;
        #pragma unroll
        for (int k2 = 0; k2 < 8; ++k2) row[lane + 64 * k2] = vals[k2] * inv;
    }
    __syncthreads();

    // ---- e-write: float2 (h-pair) per (ii,j).
    {
        float* oe = out_e + ((size_t)(b * NN) + i0) * NN * NH + hp * 2;
        #pragma unroll
        for (int k2 = 0; k2 < 4; ++k2) {
            const int fi = t + 512 * k2;          // 0..2047 = ii*512 + j
            const int ii = fi >> 9;
            const int j  = fi & 511;
            float2 o; o.x = s[ii * 2 + 0][j]; o.y = s[ii * 2 + 1][j];
            *reinterpret_cast<float2*>(oe + (size_t)ii * NN * NH + j * NH) = o;
        }
    }

    // ---- Phase 3: thread = (jg, col in h-pair slice); readlane e-broadcast.
    {
        const int col  = t & 127;
        const int jg   = t >> 7;                  // j-quarter
        const int hl   = col >> 6;                // wave-uniform
        const int lane = t & 63;
        float acc[4] = {0.f, 0.f, 0.f, 0.f};
        const float* hvb = hv + (size_t)(b * NN) * DD + hp * 128 + col;
        #pragma unroll
        for (int ch = 0; ch < 2; ++ch) {
            const int jbase = jg * 128 + ch * 64;
            const float e0 = s[0 * 2 + hl][jbase + lane];
            const float e1 = s[1 * 2 + hl][jbase + lane];
            const float e2 = s[2 * 2 + hl][jbase + lane];
            const float e3 = s[3 * 2 + hl][jbase + lane];
            for (int u = 0; u < 64; ++u) {
                const float hvv = hvb[(size_t)(jbase + u) * DD];
                acc[0] = fmaf(rl(e0, u), hvv, acc[0]);
                acc[1] = fmaf(rl(e1, u), hvv, acc[1]);
                acc[2] = fmaf(rl(e2, u), hvv, acc[2]);
                acc[3] = fmaf(rl(e3, u), hvv, acc[3]);
            }
        }
        #pragma unroll
        for (int ii = 0; ii < 4; ++ii) part[jg][ii][col] = acc[ii];
    }
    __syncthreads();
    {
        const int ii = t >> 7, col = t & 127;
        const float v = part[0][ii][col] + part[1][ii][col] + part[2][ii][col] + part[3][ii][col];
        out_hp[((size_t)(b * NN) + i0 + ii) * DD + hp * 128 + col] = v > 0.f ? v : 0.f;
    }
}

extern "C" void kernel_launch(void* const* d_in, const int* in_sizes, int n_in,
                              void* d_out, int out_size, void* d_ws, size_t ws_size,
                              hipStream_t stream) {
    const float* q   = (const float*)d_in[0];
    const float* kin = (const float*)d_in[1];
    const float* vin = (const float*)d_in[2];
    const float* wq  = (const float*)d_in[3];
    const float* bq  = (const float*)d_in[4];
    const float* wv  = (const float*)d_in[5];
    const float* bv  = (const float*)d_in[6];
    const float* a   = (const float*)d_in[7];

    float* out_hp = (float*)d_out;                    // [B,N,256]
    float* out_e  = out_hp + (size_t)NB * NN * DD;    // [B,N,N,4]

    float* hq = (float*)d_ws;                         // each B*N*256 f32
    float* hk = hq + (size_t)NB * NN * DD;
    float* hv = hk + (size_t)NB * NN * DD;

    proj_kernel<<<dim3(64, 2, 3), 256, 0, stream>>>(q, kin, vin, wq, bq, wv, bv, hq, hk, hv);
    attn_kernel<<<dim3(NB * 128 * 2), 512, 0, stream>>>(hq, hk, hv, a, out_hp, out_e);
}

// Round 6
// 131.204 us; speedup vs baseline: 1.1182x; 1.0265x over previous
//
#include <hip/hip_runtime.h>

// GraphAttentionLayer: B=2, N=512, D=256, H=4, HD=64, slope=0.2
// Inputs f32, outputs f32 = concat(h_prime [B,N,256], e [B,N,N,4]).
// lrelu(x) = 0.6x + 0.4|x|; hk-dot term is j-constant -> cancels in softmax:
// score = 0.6*sum_f hq*a + 0.4*sum_f |hq+hk|*a.
// attn grid: (b, i-tile of 4, h-pair) = 512 blocks x 512 thr -> 2 blocks/CU.
// R6: explicit load batching (16 outstanding) in phases 1 and 3 — R5 ran at
// VGPR=48 with ~66% stall; VALU work matched model, latency was unhidden.

#define NB 2
#define NN 512
#define DD 256
#define NH 4
#define HDIM 64

__device__ __forceinline__ float rl(float v, int u) {
    return __uint_as_float(__builtin_amdgcn_readlane(__float_as_uint(v), u));
}

// ---------------- proj: register-blocked GEMM, 16 rows x 128 cols/block ----
__global__ __launch_bounds__(256, 4) void proj_kernel(
    const float* __restrict__ q, const float* __restrict__ kin, const float* __restrict__ vin,
    const float* __restrict__ wq, const float* __restrict__ bq,
    const float* __restrict__ wv, const float* __restrict__ bv,
    float* __restrict__ hq, float* __restrict__ hk, float* __restrict__ hv)
{
    const int m = blockIdx.z;
    const float* x    = (m == 0) ? q  : (m == 1) ? kin : vin;
    const float* w    = (m == 2) ? wv : wq;
    const float* bias = (m == 2) ? bv : bq;
    float* out        = (m == 0) ? hq : (m == 1) ? hk : hv;

    const int r0 = blockIdx.x * 16;
    const int cb = blockIdx.y * 128;
    const int t  = threadIdx.x;

    __shared__ float xs[16][DD + 4];

    #pragma unroll
    for (int p = 0; p < 4; ++p) {
        const int idx = t + 256 * p;
        const int row = idx >> 6;
        const int kc  = idx & 63;
        const float4 v = *reinterpret_cast<const float4*>(&x[(size_t)(r0 + row) * DD + kc * 4]);
        *reinterpret_cast<float4*>(&xs[row][kc * 4]) = v;
    }
    __syncthreads();

    const int row0 = (t >> 5) * 2;
    const int c0   = (t & 31) * 4;

    const float4 b4 = *reinterpret_cast<const float4*>(&bias[cb + c0]);
    float acc[2][4];
    #pragma unroll
    for (int r = 0; r < 2; ++r) { acc[r][0]=b4.x; acc[r][1]=b4.y; acc[r][2]=b4.z; acc[r][3]=b4.w; }

    for (int kt = 0; kt < DD; kt += 4) {
        const float4 a0 = *reinterpret_cast<const float4*>(&xs[row0][kt]);
        const float4 a1 = *reinterpret_cast<const float4*>(&xs[row0 + 1][kt]);
        const float xa0[4] = {a0.x, a0.y, a0.z, a0.w};
        const float xa1[4] = {a1.x, a1.y, a1.z, a1.w};
        #pragma unroll
        for (int kk = 0; kk < 4; ++kk) {
            const float4 w4 = *reinterpret_cast<const float4*>(&w[(size_t)(kt + kk) * DD + cb + c0]);
            const float wv4[4] = {w4.x, w4.y, w4.z, w4.w};
            #pragma unroll
            for (int c = 0; c < 4; ++c) {
                acc[0][c] = fmaf(xa0[kk], wv4[c], acc[0][c]);
                acc[1][c] = fmaf(xa1[kk], wv4[c], acc[1][c]);
            }
        }
    }
    #pragma unroll
    for (int r = 0; r < 2; ++r) {
        float4 o; o.x = acc[r][0]; o.y = acc[r][1]; o.z = acc[r][2]; o.w = acc[r][3];
        *reinterpret_cast<float4*>(&out[(size_t)(r0 + row0 + r) * DD + cb + c0]) = o;
    }
}

// -------- attn: block = (b, 4 i-rows, h-pair), 512 threads, 8 waves --------
__global__ __launch_bounds__(512, 4) void attn_kernel(
    const float* __restrict__ hq, const float* __restrict__ hk, const float* __restrict__ hv,
    const float* __restrict__ a, float* __restrict__ out_hp, float* __restrict__ out_e)
{
    const int t   = threadIdx.x;
    const int b   = blockIdx.x >> 8;
    const int rem = blockIdx.x & 255;
    const int i0  = (rem >> 1) * 4;
    const int hp  = rem & 1;                      // h-pair: heads {2hp, 2hp+1}

    __shared__ float skp[4][2][HDIM + 4];         // [ii][hl][f]
    __shared__ float sa[HDIM];
    __shared__ float s[8][NN + 8];                // [ii*2+hl][j]  16.6 KB
    __shared__ float part[4][4][128];             // [jg][ii][col] 8 KB

    {   // stage hk h-slice: 4 ii x 128 cols
        const int ii = t >> 7, c = t & 127;
        skp[ii][c >> 6][c & 63] = hk[((size_t)(b * NN) + i0 + ii) * DD + hp * 128 + c];
    }
    if (t < HDIM) sa[t] = a[t];
    __syncthreads();

    // ---- Phase 1: thread = (hl, j-duo); two half-passes over f, each with a
    // 16-deep float4 load burst (both jj x 8 fc) before the FMA chain.
    {
        const int hl = t & 1;
        const int j0 = (t >> 1) * 2;
        const float* qbase = hq + ((size_t)(b * NN) + j0) * DD + (hp * 2 + hl) * HDIM;
        float accu[2] = {0.f, 0.f};
        float acc[2][4] = {};
        #pragma unroll
        for (int half = 0; half < 2; ++half) {
            float4 qb[16];                        // 16 outstanding loads
            #pragma unroll
            for (int fc = 0; fc < 8; ++fc) {
                qb[fc]     = *reinterpret_cast<const float4*>(qbase + half * 32 + fc * 4);
                qb[fc + 8] = *reinterpret_cast<const float4*>(qbase + DD + half * 32 + fc * 4);
            }
            #pragma unroll
            for (int fc = 0; fc < 8; ++fc) {
                const int fo = half * 32 + fc * 4;
                const float4 a4 = *reinterpret_cast<const float4*>(&sa[fo]);
                const float av[4] = {a4.x, a4.y, a4.z, a4.w};
                float kk[4][4];
                #pragma unroll
                for (int ii = 0; ii < 4; ++ii) {
                    const float4 kv = *reinterpret_cast<const float4*>(&skp[ii][hl][fo]);
                    kk[ii][0]=kv.x; kk[ii][1]=kv.y; kk[ii][2]=kv.z; kk[ii][3]=kv.w;
                }
                #pragma unroll
                for (int jj = 0; jj < 2; ++jj) {
                    const float4 q4 = qb[jj * 8 + fc];
                    const float qv[4] = {q4.x, q4.y, q4.z, q4.w};
                    #pragma unroll
                    for (int c = 0; c < 4; ++c) {
                        accu[jj] = fmaf(qv[c], av[c], accu[jj]);
                        #pragma unroll
                        for (int ii = 0; ii < 4; ++ii)
                            acc[jj][ii] = fmaf(__builtin_fabsf(qv[c] + kk[ii][c]), av[c], acc[jj][ii]);
                    }
                }
            }
        }
        #pragma unroll
        for (int jj = 0; jj < 2; ++jj) {
            const float su = 0.6f * accu[jj];
            #pragma unroll
            for (int ii = 0; ii < 4; ++ii)
                s[ii * 2 + hl][j0 + jj] = fmaf(0.4f, acc[jj][ii], su);
        }
    }
    __syncthreads();

    // ---- Phase 2: softmax over j; 8 waves x 8 rows -> 1 row/wave.
    {
        const int wv = t >> 6, lane = t & 63;
        float* row = &s[wv][0];
        float vals[8]; float mx = -1e30f;
        #pragma unroll
        for (int k2 = 0; k2 < 8; ++k2) { vals[k2] = row[lane + 64 * k2]; mx = fmaxf(mx, vals[k2]); }
        #pragma unroll
        for (int off = 32; off; off >>= 1) mx = fmaxf(mx, __shfl_xor(mx, off, 64));
        float sum = 0.f;
        #pragma unroll
        for (int k2 = 0; k2 < 8; ++k2) { vals[k2] = __expf(vals[k2] - mx); sum += vals[k2]; }
        #pragma unroll
        for (int off = 32; off; off >>= 1) sum += __shfl_xor(sum, off, 64);
        const float inv = 1.0f / sum;
        #pragma unroll
        for (int k2 = 0; k2 < 8; ++k2) row[lane + 64 * k2] = vals[k2] * inv;
    }
    __syncthreads();

    // ---- e-write: float2 (h-pair) per (ii,j).
    {
        float* oe = out_e + ((size_t)(b * NN) + i0) * NN * NH + hp * 2;
        #pragma unroll
        for (int k2 = 0; k2 < 4; ++k2) {
            const int fi = t + 512 * k2;          // 0..2047 = ii*512 + j
            const int ii = fi >> 9;
            const int j  = fi & 511;
            float2 o; o.x = s[ii * 2 + 0][j]; o.y = s[ii * 2 + 1][j];
            *reinterpret_cast<float2*>(oe + (size_t)ii * NN * NH + j * NH) = o;
        }
    }

    // ---- Phase 3: thread = (jg, col in h-pair slice); 16-deep hv load
    // batches, e-broadcast via readlane (VALU pipe).
    {
        const int col  = t & 127;
        const int jg   = t >> 7;                  // j-quarter
        const int hl   = col >> 6;                // wave-uniform
        const int lane = t & 63;
        float acc[4] = {0.f, 0.f, 0.f, 0.f};
        const float* hvb = hv + (size_t)(b * NN) * DD + hp * 128 + col;
        #pragma unroll
        for (int ch = 0; ch < 2; ++ch) {
            const int jbase = jg * 128 + ch * 64;
            const float e0 = s[0 * 2 + hl][jbase + lane];
            const float e1 = s[1 * 2 + hl][jbase + lane];
            const float e2 = s[2 * 2 + hl][jbase + lane];
            const float e3 = s[3 * 2 + hl][jbase + lane];
            #pragma unroll
            for (int ub = 0; ub < 4; ++ub) {
                float hvv[16];                    // 16 outstanding loads
                #pragma unroll
                for (int k = 0; k < 16; ++k)
                    hvv[k] = hvb[(size_t)(jbase + ub * 16 + k) * DD];
                #pragma unroll
                for (int k = 0; k < 16; ++k) {
                    const int u = ub * 16 + k;
                    acc[0] = fmaf(rl(e0, u), hvv[k], acc[0]);
                    acc[1] = fmaf(rl(e1, u), hvv[k], acc[1]);
                    acc[2] = fmaf(rl(e2, u), hvv[k], acc[2]);
                    acc[3] = fmaf(rl(e3, u), hvv[k], acc[3]);
                }
            }
        }
        #pragma unroll
        for (int ii = 0; ii < 4; ++ii) part[jg][ii][col] = acc[ii];
    }
    __syncthreads();
    {
        const int ii = t >> 7, col = t & 127;
        const float v = part[0][ii][col] + part[1][ii][col] + part[2][ii][col] + part[3][ii][col];
        out_hp[((size_t)(b * NN) + i0 + ii) * DD + hp * 128 + col] = v > 0.f ? v : 0.f;
    }
}

extern "C" void kernel_launch(void* const* d_in, const int* in_sizes, int n_in,
                              void* d_out, int out_size, void* d_ws, size_t ws_size,
                              hipStream_t stream) {
    const float* q   = (const float*)d_in[0];
    const float* kin = (const float*)d_in[1];
    const float* vin = (const float*)d_in[2];
    const float* wq  = (const float*)d_in[3];
    const float* bq  = (const float*)d_in[4];
    const float* wv  = (const float*)d_in[5];
    const float* bv  = (const float*)d_in[6];
    const float* a   = (const float*)d_in[7];

    float* out_hp = (float*)d_out;                    // [B,N,256]
    float* out_e  = out_hp + (size_t)NB * NN * DD;    // [B,N,N,4]

    float* hq = (float*)d_ws;                         // each B*N*256 f32
    float* hk = hq + (size_t)NB * NN * DD;
    float* hv = hk + (size_t)NB * NN * DD;

    proj_kernel<<<dim3(64, 2, 3), 256, 0, stream>>>(q, kin, vin, wq, bq, wv, bv, hq, hk, hv);
    attn_kernel<<<dim3(NB * 128 * 2), 512, 0, stream>>>(hq, hk, hv, a, out_hp, out_e);
}

// Round 7
// 122.616 us; speedup vs baseline: 1.1966x; 1.0700x over previous
//
#include <hip/hip_runtime.h>

// GraphAttentionLayer: B=2, N=512, D=256, H=4, HD=64, slope=0.2
// Inputs f32, outputs f32 = concat(h_prime [B,N,256], e [B,N,N,4]).
// lrelu(x) = 0.6x + 0.4|x|; hk-dot term is j-constant -> cancels in softmax:
// score = 0.6*sum_f hq*a + 0.4*sum_f |hq+hk|*a.
// R7: block = (b, 4 i-rows, single h), 256 thr, grid 1024 -> 4 blocks/CU
// co-resident; hk/a via wave-uniform scalar loads (no staging barrier);
// sched_barrier(0) pins 16-deep load bursts (R6's were compiler-defeated,
// VGPR stayed 48).

#define NB 2
#define NN 512
#define DD 256
#define NH 4
#define HDIM 64

__device__ __forceinline__ float rl(float v, int u) {
    return __uint_as_float(__builtin_amdgcn_readlane(__float_as_uint(v), u));
}

// ---------------- proj: register-blocked GEMM, 16 rows x 128 cols/block ----
__global__ __launch_bounds__(256, 4) void proj_kernel(
    const float* __restrict__ q, const float* __restrict__ kin, const float* __restrict__ vin,
    const float* __restrict__ wq, const float* __restrict__ bq,
    const float* __restrict__ wv, const float* __restrict__ bv,
    float* __restrict__ hq, float* __restrict__ hk, float* __restrict__ hv)
{
    const int m = blockIdx.z;
    const float* x    = (m == 0) ? q  : (m == 1) ? kin : vin;
    const float* w    = (m == 2) ? wv : wq;
    const float* bias = (m == 2) ? bv : bq;
    float* out        = (m == 0) ? hq : (m == 1) ? hk : hv;

    const int r0 = blockIdx.x * 16;
    const int cb = blockIdx.y * 128;
    const int t  = threadIdx.x;

    __shared__ float xs[16][DD + 4];

    #pragma unroll
    for (int p = 0; p < 4; ++p) {
        const int idx = t + 256 * p;
        const int row = idx >> 6;
        const int kc  = idx & 63;
        const float4 v = *reinterpret_cast<const float4*>(&x[(size_t)(r0 + row) * DD + kc * 4]);
        *reinterpret_cast<float4*>(&xs[row][kc * 4]) = v;
    }
    __syncthreads();

    const int row0 = (t >> 5) * 2;
    const int c0   = (t & 31) * 4;

    const float4 b4 = *reinterpret_cast<const float4*>(&bias[cb + c0]);
    float acc[2][4];
    #pragma unroll
    for (int r = 0; r < 2; ++r) { acc[r][0]=b4.x; acc[r][1]=b4.y; acc[r][2]=b4.z; acc[r][3]=b4.w; }

    for (int kt = 0; kt < DD; kt += 4) {
        const float4 a0 = *reinterpret_cast<const float4*>(&xs[row0][kt]);
        const float4 a1 = *reinterpret_cast<const float4*>(&xs[row0 + 1][kt]);
        const float xa0[4] = {a0.x, a0.y, a0.z, a0.w};
        const float xa1[4] = {a1.x, a1.y, a1.z, a1.w};
        #pragma unroll
        for (int kk = 0; kk < 4; ++kk) {
            const float4 w4 = *reinterpret_cast<const float4*>(&w[(size_t)(kt + kk) * DD + cb + c0]);
            const float wv4[4] = {w4.x, w4.y, w4.z, w4.w};
            #pragma unroll
            for (int c = 0; c < 4; ++c) {
                acc[0][c] = fmaf(xa0[kk], wv4[c], acc[0][c]);
                acc[1][c] = fmaf(xa1[kk], wv4[c], acc[1][c]);
            }
        }
    }
    #pragma unroll
    for (int r = 0; r < 2; ++r) {
        float4 o; o.x = acc[r][0]; o.y = acc[r][1]; o.z = acc[r][2]; o.w = acc[r][3];
        *reinterpret_cast<float4*>(&out[(size_t)(r0 + row0 + r) * DD + cb + c0]) = o;
    }
}

// ------ attn: block = (b, 4 i-rows, one head), 256 threads, 4 waves --------
__global__ __launch_bounds__(256, 4) void attn_kernel(
    const float* __restrict__ hq, const float* __restrict__ hk, const float* __restrict__ hv,
    const float* __restrict__ a, float* __restrict__ out_hp, float* __restrict__ out_e)
{
    const int t   = threadIdx.x;
    const int b   = blockIdx.x >> 9;
    const int rem = blockIdx.x & 511;
    const int i0  = (rem >> 2) * 4;
    const int h   = rem & 3;

    __shared__ float s[4][NN + 8];                // [ii][j]  8.3 KB
    __shared__ float part[4][4][HDIM];            // [jg][ii][col] 4 KB

    const float* hk0 = hk + ((size_t)(b * NN) + i0) * DD + h * HDIM;  // wave-uniform

    // ---- Phase 1: thread = j-duo; hk/a via scalar loads; 16-deep q bursts.
    {
        const int j0 = t * 2;
        const float* qbase = hq + ((size_t)(b * NN) + j0) * DD + h * HDIM;
        float accu[2] = {0.f, 0.f};
        float acc[2][4] = {};
        #pragma unroll
        for (int half = 0; half < 2; ++half) {
            float4 qb[16];                        // 16 outstanding loads (64 VGPR)
            #pragma unroll
            for (int fc = 0; fc < 8; ++fc) {
                qb[fc]     = *reinterpret_cast<const float4*>(qbase + half * 32 + fc * 4);
                qb[fc + 8] = *reinterpret_cast<const float4*>(qbase + DD + half * 32 + fc * 4);
            }
            __builtin_amdgcn_sched_barrier(0);    // pin: all 16 loads issue first
            #pragma unroll
            for (int fc = 0; fc < 8; ++fc) {
                const int fo = half * 32 + fc * 4;
                const float4 a4 = *reinterpret_cast<const float4*>(a + fo);       // uniform -> SMEM
                const float av[4] = {a4.x, a4.y, a4.z, a4.w};
                float kk[4][4];
                #pragma unroll
                for (int ii = 0; ii < 4; ++ii) {
                    const float4 kv = *reinterpret_cast<const float4*>(hk0 + ii * DD + fo); // uniform
                    kk[ii][0]=kv.x; kk[ii][1]=kv.y; kk[ii][2]=kv.z; kk[ii][3]=kv.w;
                }
                #pragma unroll
                for (int jj = 0; jj < 2; ++jj) {
                    const float4 q4 = qb[jj * 8 + fc];
                    const float qv[4] = {q4.x, q4.y, q4.z, q4.w};
                    #pragma unroll
                    for (int c = 0; c < 4; ++c) {
                        accu[jj] = fmaf(qv[c], av[c], accu[jj]);
                        #pragma unroll
                        for (int ii = 0; ii < 4; ++ii)
                            acc[jj][ii] = fmaf(__builtin_fabsf(qv[c] + kk[ii][c]), av[c], acc[jj][ii]);
                    }
                }
            }
        }
        #pragma unroll
        for (int jj = 0; jj < 2; ++jj) {
            const float su = 0.6f * accu[jj];
            #pragma unroll
            for (int ii = 0; ii < 4; ++ii)
                s[ii][j0 + jj] = fmaf(0.4f, acc[jj][ii], su);
        }
    }
    __syncthreads();

    // ---- Phase 2: softmax over j; 4 waves x 4 rows -> 1 row/wave.
    {
        const int wv = t >> 6, lane = t & 63;
        float* row = &s[wv][0];
        float vals[8]; float mx = -1e30f;
        #pragma unroll
        for (int k2 = 0; k2 < 8; ++k2) { vals[k2] = row[lane + 64 * k2]; mx = fmaxf(mx, vals[k2]); }
        #pragma unroll
        for (int off = 32; off; off >>= 1) mx = fmaxf(mx, __shfl_xor(mx, off, 64));
        float sum = 0.f;
        #pragma unroll
        for (int k2 = 0; k2 < 8; ++k2) { vals[k2] = __expf(vals[k2] - mx); sum += vals[k2]; }
        #pragma unroll
        for (int off = 32; off; off >>= 1) sum += __shfl_xor(sum, off, 64);
        const float inv = 1.0f / sum;
        #pragma unroll
        for (int k2 = 0; k2 < 8; ++k2) row[lane + 64 * k2] = vals[k2] * inv;
    }
    __syncthreads();

    // ---- e-write: out_e[b,i0+ii,j,h], stride-NH scalar stores.
    {
        float* oe = out_e + (((size_t)(b * NN) + i0) * NN) * NH + h;
        #pragma unroll
        for (int k2 = 0; k2 < 8; ++k2) {
            const int idx = t + 256 * k2;         // 0..2047 = ii*512 + j
            const int ii = idx >> 9;
            const int j  = idx & 511;
            oe[((size_t)ii * NN + j) * NH] = s[ii][j];
        }
    }

    // ---- Phase 3: thread = (jg, col); 16-deep hv bursts; readlane e-bcast.
    {
        const int col  = t & 63;
        const int jg   = t >> 6;                  // j-quarter (128 j each)
        const int lane = t & 63;
        float acc4[4] = {0.f, 0.f, 0.f, 0.f};
        const float* hvb = hv + (size_t)(b * NN) * DD + h * HDIM + col;
        #pragma unroll
        for (int ch = 0; ch < 2; ++ch) {
            const int jbase = jg * 128 + ch * 64;
            const float e0 = s[0][jbase + lane];
            const float e1 = s[1][jbase + lane];
            const float e2 = s[2][jbase + lane];
            const float e3 = s[3][jbase + lane];
            #pragma unroll
            for (int ub = 0; ub < 4; ++ub) {
                float hvv[16];                    // 16 outstanding loads
                #pragma unroll
                for (int k = 0; k < 16; ++k)
                    hvv[k] = hvb[(size_t)(jbase + ub * 16 + k) * DD];
                __builtin_amdgcn_sched_barrier(0);
                #pragma unroll
                for (int k = 0; k < 16; ++k) {
                    const int u = ub * 16 + k;
                    acc4[0] = fmaf(rl(e0, u), hvv[k], acc4[0]);
                    acc4[1] = fmaf(rl(e1, u), hvv[k], acc4[1]);
                    acc4[2] = fmaf(rl(e2, u), hvv[k], acc4[2]);
                    acc4[3] = fmaf(rl(e3, u), hvv[k], acc4[3]);
                }
            }
        }
        #pragma unroll
        for (int ii = 0; ii < 4; ++ii) part[jg][ii][col] = acc4[ii];
    }
    __syncthreads();
    {
        const int ii = t >> 6, col = t & 63;
        const float v = part[0][ii][col] + part[1][ii][col] + part[2][ii][col] + part[3][ii][col];
        out_hp[((size_t)(b * NN) + i0 + ii) * DD + h * HDIM + col] = v > 0.f ? v : 0.f;
    }
}

extern "C" void kernel_launch(void* const* d_in, const int* in_sizes, int n_in,
                              void* d_out, int out_size, void* d_ws, size_t ws_size,
                              hipStream_t stream) {
    const float* q   = (const float*)d_in[0];
    const float* kin = (const float*)d_in[1];
    const float* vin = (const float*)d_in[2];
    const float* wq  = (const float*)d_in[3];
    const float* bq  = (const float*)d_in[4];
    const float* wv  = (const float*)d_in[5];
    const float* bv  = (const float*)d_in[6];
    const float* a   = (const float*)d_in[7];

    float* out_hp = (float*)d_out;                    // [B,N,256]
    float* out_e  = out_hp + (size_t)NB * NN * DD;    // [B,N,N,4]

    float* hq = (float*)d_ws;                         // each B*N*256 f32
    float* hk = hq + (size_t)NB * NN * DD;
    float* hv = hk + (size_t)NB * NN * DD;

    proj_kernel<<<dim3(64, 2, 3), 256, 0, stream>>>(q, kin, vin, wq, bq, wv, bv, hq, hk, hv);
    attn_kernel<<<dim3(NB * 128 * NH), 256, 0, stream>>>(hq, hk, hv, a, out_hp, out_e);
}

// Round 8
// 120.411 us; speedup vs baseline: 1.2185x; 1.0183x over previous
//
#include <hip/hip_runtime.h>

// GraphAttentionLayer: B=2, N=512, D=256, H=4, HD=64, slope=0.2
// Inputs f32, outputs f32 = concat(h_prime [B,N,256], e [B,N,N,4]).
// lrelu(x) = 0.6x + 0.4|x|; hk-dot term is j-constant -> cancels in softmax:
// score = 0.6*sum_f hq*a + 0.4*sum_f |hq+hk|*a.
// R8: attn is ~90% VALU-issue-bound (R7 counters); phases 1/3 rewritten with
// packed f32 (v_pk_add/pk_max-neg/pk_fma via ext_vector_type(2)) to cut the
// issue count ~25%. |t| computed as max(t,-t) so neg folds into VOP3P.

#define NB 2
#define NN 512
#define DD 256
#define NH 4
#define HDIM 64

typedef __attribute__((ext_vector_type(2))) float f32x2;

__device__ __forceinline__ float rl(float v, int u) {
    return __uint_as_float(__builtin_amdgcn_readlane(__float_as_uint(v), u));
}
__device__ __forceinline__ f32x2 pk_fma(f32x2 a, f32x2 b, f32x2 c) {
    return __builtin_elementwise_fma(a, b, c);
}
__device__ __forceinline__ f32x2 pk_abs(f32x2 t) {
    return __builtin_elementwise_max(t, -t);     // v_pk_max_f32 with neg mod
}

// ---------------- proj: register-blocked GEMM, 16 rows x 128 cols/block ----
__global__ __launch_bounds__(256, 4) void proj_kernel(
    const float* __restrict__ q, const float* __restrict__ kin, const float* __restrict__ vin,
    const float* __restrict__ wq, const float* __restrict__ bq,
    const float* __restrict__ wv, const float* __restrict__ bv,
    float* __restrict__ hq, float* __restrict__ hk, float* __restrict__ hv)
{
    const int m = blockIdx.z;
    const float* x    = (m == 0) ? q  : (m == 1) ? kin : vin;
    const float* w    = (m == 2) ? wv : wq;
    const float* bias = (m == 2) ? bv : bq;
    float* out        = (m == 0) ? hq : (m == 1) ? hk : hv;

    const int r0 = blockIdx.x * 16;
    const int cb = blockIdx.y * 128;
    const int t  = threadIdx.x;

    __shared__ float xs[16][DD + 4];

    #pragma unroll
    for (int p = 0; p < 4; ++p) {
        const int idx = t + 256 * p;
        const int row = idx >> 6;
        const int kc  = idx & 63;
        const float4 v = *reinterpret_cast<const float4*>(&x[(size_t)(r0 + row) * DD + kc * 4]);
        *reinterpret_cast<float4*>(&xs[row][kc * 4]) = v;
    }
    __syncthreads();

    const int row0 = (t >> 5) * 2;
    const int c0   = (t & 31) * 4;

    const float4 b4 = *reinterpret_cast<const float4*>(&bias[cb + c0]);
    float acc[2][4];
    #pragma unroll
    for (int r = 0; r < 2; ++r) { acc[r][0]=b4.x; acc[r][1]=b4.y; acc[r][2]=b4.z; acc[r][3]=b4.w; }

    for (int kt = 0; kt < DD; kt += 4) {
        const float4 a0 = *reinterpret_cast<const float4*>(&xs[row0][kt]);
        const float4 a1 = *reinterpret_cast<const float4*>(&xs[row0 + 1][kt]);
        const float xa0[4] = {a0.x, a0.y, a0.z, a0.w};
        const float xa1[4] = {a1.x, a1.y, a1.z, a1.w};
        #pragma unroll
        for (int kk = 0; kk < 4; ++kk) {
            const float4 w4 = *reinterpret_cast<const float4*>(&w[(size_t)(kt + kk) * DD + cb + c0]);
            const float wv4[4] = {w4.x, w4.y, w4.z, w4.w};
            #pragma unroll
            for (int c = 0; c < 4; ++c) {
                acc[0][c] = fmaf(xa0[kk], wv4[c], acc[0][c]);
                acc[1][c] = fmaf(xa1[kk], wv4[c], acc[1][c]);
            }
        }
    }
    #pragma unroll
    for (int r = 0; r < 2; ++r) {
        float4 o; o.x = acc[r][0]; o.y = acc[r][1]; o.z = acc[r][2]; o.w = acc[r][3];
        *reinterpret_cast<float4*>(&out[(size_t)(r0 + row0 + r) * DD + cb + c0]) = o;
    }
}

// ------ attn: block = (b, 4 i-rows, one head), 256 threads, 4 waves --------
__global__ __launch_bounds__(256, 4) void attn_kernel(
    const float* __restrict__ hq, const float* __restrict__ hk, const float* __restrict__ hv,
    const float* __restrict__ a, float* __restrict__ out_hp, float* __restrict__ out_e)
{
    const int t   = threadIdx.x;
    const int b   = blockIdx.x >> 9;
    const int rem = blockIdx.x & 511;
    const int i0  = (rem >> 2) * 4;
    const int h   = rem & 3;

    __shared__ float s[4][NN + 8];                // [ii][j]  8.3 KB
    __shared__ float part[4][4][HDIM];            // [jg][ii][col] 4 KB

    const float* hk0 = hk + ((size_t)(b * NN) + i0) * DD + h * HDIM;  // wave-uniform

    // ---- Phase 1: thread = j-duo; packed f32 math; 16-deep q bursts.
    {
        const int j0 = t * 2;
        const float* qbase = hq + ((size_t)(b * NN) + j0) * DD + h * HDIM;
        f32x2 accu[2] = {{0.f, 0.f}, {0.f, 0.f}};
        f32x2 acc[2][4] = {};
        #pragma unroll
        for (int half = 0; half < 2; ++half) {
            float4 qb[16];                        // 16 outstanding loads (64 VGPR)
            #pragma unroll
            for (int fc = 0; fc < 8; ++fc) {
                qb[fc]     = *reinterpret_cast<const float4*>(qbase + half * 32 + fc * 4);
                qb[fc + 8] = *reinterpret_cast<const float4*>(qbase + DD + half * 32 + fc * 4);
            }
            __builtin_amdgcn_sched_barrier(0);    // pin: all 16 loads issue first
            #pragma unroll
            for (int fc = 0; fc < 8; ++fc) {
                const int fo = half * 32 + fc * 4;
                const float4 a4 = *reinterpret_cast<const float4*>(a + fo);       // uniform
                const f32x2 av[2] = {{a4.x, a4.y}, {a4.z, a4.w}};
                f32x2 kk[4][2];
                #pragma unroll
                for (int ii = 0; ii < 4; ++ii) {
                    const float4 kv = *reinterpret_cast<const float4*>(hk0 + ii * DD + fo); // uniform
                    kk[ii][0] = f32x2{kv.x, kv.y}; kk[ii][1] = f32x2{kv.z, kv.w};
                }
                #pragma unroll
                for (int jj = 0; jj < 2; ++jj) {
                    const float4 q4 = qb[jj * 8 + fc];
                    const f32x2 qv[2] = {{q4.x, q4.y}, {q4.z, q4.w}};
                    #pragma unroll
                    for (int cp = 0; cp < 2; ++cp) {
                        accu[jj] = pk_fma(qv[cp], av[cp], accu[jj]);          // v_pk_fma
                        #pragma unroll
                        for (int ii = 0; ii < 4; ++ii) {
                            const f32x2 t2 = qv[cp] + kk[ii][cp];             // v_pk_add
                            acc[jj][ii] = pk_fma(pk_abs(t2), av[cp], acc[jj][ii]);
                        }
                    }
                }
            }
        }
        #pragma unroll
        for (int jj = 0; jj < 2; ++jj) {
            const float su = 0.6f * (accu[jj].x + accu[jj].y);
            #pragma unroll
            for (int ii = 0; ii < 4; ++ii)
                s[ii][j0 + jj] = fmaf(0.4f, acc[jj][ii].x + acc[jj][ii].y, su);
        }
    }
    __syncthreads();

    // ---- Phase 2: softmax over j; 4 waves x 4 rows -> 1 row/wave.
    {
        const int wv = t >> 6, lane = t & 63;
        float* row = &s[wv][0];
        float vals[8]; float mx = -1e30f;
        #pragma unroll
        for (int k2 = 0; k2 < 8; ++k2) { vals[k2] = row[lane + 64 * k2]; mx = fmaxf(mx, vals[k2]); }
        #pragma unroll
        for (int off = 32; off; off >>= 1) mx = fmaxf(mx, __shfl_xor(mx, off, 64));
        float sum = 0.f;
        #pragma unroll
        for (int k2 = 0; k2 < 8; ++k2) { vals[k2] = __expf(vals[k2] - mx); sum += vals[k2]; }
        #pragma unroll
        for (int off = 32; off; off >>= 1) sum += __shfl_xor(sum, off, 64);
        const float inv = 1.0f / sum;
        #pragma unroll
        for (int k2 = 0; k2 < 8; ++k2) row[lane + 64 * k2] = vals[k2] * inv;
    }
    __syncthreads();

    // ---- e-write: out_e[b,i0+ii,j,h], stride-NH scalar stores.
    {
        float* oe = out_e + (((size_t)(b * NN) + i0) * NN) * NH + h;
        #pragma unroll
        for (int k2 = 0; k2 < 8; ++k2) {
            const int idx = t + 256 * k2;         // 0..2047 = ii*512 + j
            const int ii = idx >> 9;
            const int j  = idx & 511;
            oe[((size_t)ii * NN + j) * NH] = s[ii][j];
        }
    }

    // ---- Phase 3: thread = (jg, col); 16-deep hv bursts; packed u-pairs.
    {
        const int col  = t & 63;
        const int jg   = t >> 6;                  // j-quarter (128 j each)
        const int lane = t & 63;
        f32x2 acc2[4] = {};
        const float* hvb = hv + (size_t)(b * NN) * DD + h * HDIM + col;
        #pragma unroll
        for (int ch = 0; ch < 2; ++ch) {
            const int jbase = jg * 128 + ch * 64;
            const float e0 = s[0][jbase + lane];
            const float e1 = s[1][jbase + lane];
            const float e2 = s[2][jbase + lane];
            const float e3 = s[3][jbase + lane];
            #pragma unroll
            for (int ub = 0; ub < 4; ++ub) {
                float hvv[16];                    // 16 outstanding loads
                #pragma unroll
                for (int k = 0; k < 16; ++k)
                    hvv[k] = hvb[(size_t)(jbase + ub * 16 + k) * DD];
                __builtin_amdgcn_sched_barrier(0);
                #pragma unroll
                for (int k = 0; k < 16; k += 2) {
                    const int u = ub * 16 + k;
                    const f32x2 hv2 = {hvv[k], hvv[k + 1]};
                    acc2[0] = pk_fma(f32x2{rl(e0, u), rl(e0, u + 1)}, hv2, acc2[0]);
                    acc2[1] = pk_fma(f32x2{rl(e1, u), rl(e1, u + 1)}, hv2, acc2[1]);
                    acc2[2] = pk_fma(f32x2{rl(e2, u), rl(e2, u + 1)}, hv2, acc2[2]);
                    acc2[3] = pk_fma(f32x2{rl(e3, u), rl(e3, u + 1)}, hv2, acc2[3]);
                }
            }
        }
        #pragma unroll
        for (int ii = 0; ii < 4; ++ii) part[jg][ii][col] = acc2[ii].x + acc2[ii].y;
    }
    __syncthreads();
    {
        const int ii = t >> 6, col = t & 63;
        const float v = part[0][ii][col] + part[1][ii][col] + part[2][ii][col] + part[3][ii][col];
        out_hp[((size_t)(b * NN) + i0 + ii) * DD + h * HDIM + col] = v > 0.f ? v : 0.f;
    }
}

extern "C" void kernel_launch(void* const* d_in, const int* in_sizes, int n_in,
                              void* d_out, int out_size, void* d_ws, size_t ws_size,
                              hipStream_t stream) {
    const float* q   = (const float*)d_in[0];
    const float* kin = (const float*)d_in[1];
    const float* vin = (const float*)d_in[2];
    const float* wq  = (const float*)d_in[3];
    const float* bq  = (const float*)d_in[4];
    const float* wv  = (const float*)d_in[5];
    const float* bv  = (const float*)d_in[6];
    const float* a   = (const float*)d_in[7];

    float* out_hp = (float*)d_out;                    // [B,N,256]
    float* out_e  = out_hp + (size_t)NB * NN * DD;    // [B,N,N,4]

    float* hq = (float*)d_ws;                         // each B*N*256 f32
    float* hk = hq + (size_t)NB * NN * DD;
    float* hv = hk + (size_t)NB * NN * DD;

    proj_kernel<<<dim3(64, 2, 3), 256, 0, stream>>>(q, kin, vin, wq, bq, wv, bv, hq, hk, hv);
    attn_kernel<<<dim3(NB * 128 * NH), 256, 0, stream>>>(hq, hk, hv, a, out_hp, out_e);
}